// Round 5
// baseline (129.410 us; speedup 1.0000x reference)
//
#include <hip/hip_runtime.h>
#include <hip/hip_bf16.h>
#include <math.h>

#define NN 8192
#define DD 128
#define MARGIN_F 1.0f
#define BIGF 3.402823466e+38f

typedef __attribute__((ext_vector_type(8))) short short8;
typedef __attribute__((ext_vector_type(4))) float f32x4;

// ---------------- prep: fp32 -> bf16 convert + exact fp32 row norms ----------------
// grid.y = 0 -> A, 1 -> B
__global__ __launch_bounds__(256) void prep_kernel(const float* __restrict__ A,
                                                   const float* __restrict__ B,
                                                   __hip_bfloat16* __restrict__ Abf,
                                                   __hip_bfloat16* __restrict__ Bbf,
                                                   float* __restrict__ na,
                                                   float* __restrict__ nb) {
    const float* x = blockIdx.y ? B : A;
    __hip_bfloat16* xb = blockIdx.y ? Bbf : Abf;
    float* norm = blockIdx.y ? nb : na;
    int lane = threadIdx.x & 63;
    int row  = blockIdx.x * 4 + (threadIdx.x >> 6);
    const float2 v = *(const float2*)(x + (size_t)row * DD + lane * 2);
    float s = v.x * v.x + v.y * v.y;
    __hip_bfloat162 h;
    h.x = __float2bfloat16(v.x);
    h.y = __float2bfloat16(v.y);
    *(__hip_bfloat162*)(xb + (size_t)row * DD + lane * 2) = h;
#pragma unroll
    for (int off = 32; off >= 1; off >>= 1) s += __shfl_xor(s, off, 64);
    if (lane == 0) norm[row] = s;
}

// ---------------- main MFMA distance pass ----------------
// 128x128 tile per block, 4 waves (2x2), each wave 64x64 = 4x4 frags of 16x16x32.
// K staged in two 64-wide phases -> 32 KB LDS.
// __launch_bounds__(256,2): VGPR cap 256 -> compiler allocates ~88, NO SPILL
// (R3/R4 lesson: tighter caps force accumulator spills, 20-36 MB scratch traffic).
// PASS 0: f32 min of d^2 per row/col via u32 atomicMin (valid for d2>=0).
// PASS 1: hinge sums over ALL elements; argmin hinge == MARGIN exactly, fixed
//         in the finalizer by subtracting N+M.
template <int PASS>
__global__ __launch_bounds__(256, 2) void dist_mfma(
    const __hip_bfloat16* __restrict__ Ab, const __hip_bfloat16* __restrict__ Bb,
    const float* __restrict__ na, const float* __restrict__ nb,
    unsigned int* __restrict__ rowmin, unsigned int* __restrict__ colmin,
    const float* __restrict__ rowp1m, const float* __restrict__ colp1m,
    float* __restrict__ partial) {
    __shared__ char lds[32768];
    char* ldsA = lds;
    char* ldsB = lds + 16384;
    const int tid = threadIdx.x;
    const int rowBase = blockIdx.y * 128;
    const int colBase = blockIdx.x * 128;

    const unsigned short* aG = (const unsigned short*)Ab + (size_t)rowBase * DD;
    const unsigned short* bG = (const unsigned short*)Bb + (size_t)colBase * DD;

    const int l = tid & 63, wid = tid >> 6;
    const int wr = wid >> 1, wc = wid & 1;   // wave 64x64 sub-tile
    const int g = l >> 4, c = l & 15;

    f32x4 acc[4][4];
#pragma unroll
    for (int mi = 0; mi < 4; ++mi)
#pragma unroll
        for (int ni = 0; ni < 4; ++ni) acc[mi][ni] = (f32x4)0.f;

#pragma unroll
    for (int p = 0; p < 2; ++p) {
        if (p) __syncthreads();   // previous compute done before overwrite
        // stage 128 rows x 64 bf16 (128 B/row) of A and B, XOR-swizzled
#pragma unroll
        for (int it = 0; it < 4; ++it) {
            int idx = tid + 256 * it;   // 0..1023
            int r = idx >> 3;           // row 0..127
            int c16 = idx & 7;          // 16B chunk in row
            int dst = r * 128 + ((c16 * 16) ^ ((r & 7) << 4));
            *(short8*)(ldsA + dst) = *(const short8*)(aG + r * DD + p * 64 + c16 * 8);
            *(short8*)(ldsB + dst) = *(const short8*)(bG + r * DD + p * 64 + c16 * 8);
        }
        __syncthreads();
#pragma unroll
        for (int kk = 0; kk < 2; ++kk) {
            short8 af[4], bf[4];
            const int kbyte = kk * 64 + g * 16;
#pragma unroll
            for (int mi = 0; mi < 4; ++mi) {
                int r = wr * 64 + mi * 16 + c;
                af[mi] = *(const short8*)(ldsA + r * 128 + (kbyte ^ ((r & 7) << 4)));
            }
#pragma unroll
            for (int ni = 0; ni < 4; ++ni) {
                int r2 = wc * 64 + ni * 16 + c;
                bf[ni] = *(const short8*)(ldsB + r2 * 128 + (kbyte ^ ((r2 & 7) << 4)));
            }
#pragma unroll
            for (int mi = 0; mi < 4; ++mi)
#pragma unroll
                for (int ni = 0; ni < 4; ++ni)
                    acc[mi][ni] = __builtin_amdgcn_mfma_f32_16x16x32_bf16(
                        af[mi], bf[ni], acc[mi][ni], 0, 0, 0);
        }
    }

    // out_row = row0 + mi*16 + g*4 + reg ; out_col = col0 + ni*16 + c
    const int row0 = rowBase + wr * 64;
    const int col0 = colBase + wc * 64;

    if (PASS == 0) {
        float nbc[4];
#pragma unroll
        for (int ni = 0; ni < 4; ++ni) nbc[ni] = nb[col0 + ni * 16 + c];
        float colm[4] = {BIGF, BIGF, BIGF, BIGF};
#pragma unroll
        for (int mi = 0; mi < 4; ++mi) {
            const f32x4 na4 = *(const f32x4*)(na + row0 + mi * 16 + g * 4);
            float rowm[4] = {BIGF, BIGF, BIGF, BIGF};
#pragma unroll
            for (int ni = 0; ni < 4; ++ni) {
                f32x4 a = acc[mi][ni];
#pragma unroll
                for (int reg = 0; reg < 4; ++reg) {
                    float d2 = fmaf(-2.0f, a[reg], na4[reg] + nbc[ni]);
                    rowm[reg] = fminf(rowm[reg], d2);
                    colm[ni] = fminf(colm[ni], d2);
                }
            }
#pragma unroll
            for (int reg = 0; reg < 4; ++reg) {
                float m = rowm[reg];
                m = fminf(m, __shfl_xor(m, 1, 64));
                m = fminf(m, __shfl_xor(m, 2, 64));
                m = fminf(m, __shfl_xor(m, 4, 64));
                m = fminf(m, __shfl_xor(m, 8, 64));
                rowm[reg] = m;
            }
            if (c == 0) {
#pragma unroll
                for (int reg = 0; reg < 4; ++reg)
                    atomicMin(&rowmin[row0 + mi * 16 + g * 4 + reg],
                              __float_as_uint(rowm[reg]));
            }
        }
#pragma unroll
        for (int ni = 0; ni < 4; ++ni) {
            float m = colm[ni];
            m = fminf(m, __shfl_xor(m, 16, 64));
            m = fminf(m, __shfl_xor(m, 32, 64));
            if (g == 0) atomicMin(&colmin[col0 + ni * 16 + c], __float_as_uint(m));
        }
    } else {
        float nbc[4], cp1[4];
#pragma unroll
        for (int ni = 0; ni < 4; ++ni) {
            int col = col0 + ni * 16 + c;
            nbc[ni] = nb[col];
            cp1[ni] = colp1m[col];
        }
        float tot = 0.f;
#pragma unroll
        for (int mi = 0; mi < 4; ++mi) {
            const int rbase = row0 + mi * 16 + g * 4;
            const f32x4 na4 = *(const f32x4*)(na + rbase);
            const f32x4 rp1 = *(const f32x4*)(rowp1m + rbase);
#pragma unroll
            for (int ni = 0; ni < 4; ++ni) {
                f32x4 a = acc[mi][ni];
#pragma unroll
                for (int reg = 0; reg < 4; ++reg) {
                    float d2 = fmaf(-2.0f, a[reg], na4[reg] + nbc[ni]);
                    float d = __builtin_amdgcn_sqrtf(fmaxf(d2, 0.f));
                    tot += fmaxf(0.f, rp1[reg] + d) + fmaxf(0.f, cp1[ni] + d);
                }
            }
        }
#pragma unroll
        for (int off = 32; off >= 1; off >>= 1) tot += __shfl_xor(tot, off, 64);
        __syncthreads();   // all waves done reading LDS tiles
        float* red = (float*)lds;
        if (l == 0) red[wid] = tot;
        __syncthreads();
        if (tid == 0)
            atomicAdd(&partial[blockIdx.y], red[0] + red[1] + red[2] + red[3]);
    }
}

// ---------------- mid: (MARGIN - sqrt(min d^2)) for rows & cols ----------------
__global__ __launch_bounds__(256) void mid_kernel(const unsigned int* __restrict__ minbits,
                                                  float* __restrict__ p1m) {
    int i = blockIdx.x * 256 + threadIdx.x;   // 16384 = rows then cols
    float m = __uint_as_float(minbits[i]);
    p1m[i] = MARGIN_F - __builtin_amdgcn_sqrtf(fmaxf(m, 0.f));
}

// ---------------- final scalar ----------------
__global__ __launch_bounds__(64) void final_kernel(const float* __restrict__ partial,
                                                   float* __restrict__ out) {
    float s = partial[threadIdx.x];   // 64 partials
#pragma unroll
    for (int off = 32; off >= 1; off >>= 1) s += __shfl_xor(s, off, 64);
    if (threadIdx.x == 0) {
        // subtract the argmin hinge (exactly MARGIN=1.0) for each of N rows + M cols
        out[0] = (s - 16384.0f) * (0.5f / (8192.0f * 8192.0f));
    }
}

extern "C" void kernel_launch(void* const* d_in, const int* in_sizes, int n_in,
                              void* d_out, int out_size, void* d_ws, size_t ws_size,
                              hipStream_t stream) {
    const float* A = (const float*)d_in[0];
    const float* B = (const float*)d_in[1];
    char* ws = (char*)d_ws;

    const size_t MB = 1024 * 1024;
    __hip_bfloat16* Abf = (__hip_bfloat16*)(ws);                 // 2 MB
    __hip_bfloat16* Bbf = (__hip_bfloat16*)(ws + 2 * MB);        // 2 MB
    float* na            = (float*)(ws + 4 * MB);                // 32 KB
    float* nb            = (float*)(ws + 4 * MB + 32768);        // 32 KB
    unsigned int* rowmin = (unsigned int*)(ws + 4 * MB + 65536); // 32 KB
    unsigned int* colmin = (unsigned int*)(ws + 4 * MB + 98304); // 32 KB (contig after rowmin)
    float* rowp1m        = (float*)(ws + 4 * MB + 131072);       // 32 KB
    float* colp1m        = (float*)(ws + 4 * MB + 163840);       // 32 KB (contig after rowp1m)
    float* partial       = (float*)(ws + 4 * MB + 196608);       // 256 B

    hipMemsetAsync(rowmin, 0xFF, 65536, stream);   // rowmin+colmin -> u32 max
    hipMemsetAsync(partial, 0, 256, stream);

    dim3 pgrid(NN / 4, 2);
    prep_kernel<<<pgrid, 256, 0, stream>>>(A, B, Abf, Bbf, na, nb);

    dim3 grid(NN / 128, NN / 128);
    dist_mfma<0><<<grid, 256, 0, stream>>>(Abf, Bbf, na, nb, rowmin, colmin,
                                           nullptr, nullptr, nullptr);
    mid_kernel<<<16384 / 256, 256, 0, stream>>>(rowmin, rowp1m);
    dist_mfma<1><<<grid, 256, 0, stream>>>(Abf, Bbf, na, nb, nullptr, nullptr,
                                           rowp1m, colp1m, partial);
    final_kernel<<<1, 64, 0, stream>>>(partial, (float*)d_out);
}

// Round 6
// 92.220 us; speedup vs baseline: 1.4033x; 1.4033x over previous
//
#include <hip/hip_runtime.h>
#include <hip/hip_bf16.h>
#include <math.h>

#define NN 8192
#define DD 128
#define BIGF 3.402823466e+38f

typedef __attribute__((ext_vector_type(8))) short short8;
typedef __attribute__((ext_vector_type(4))) float f32x4;

// ---------------- prep: fp32 -> bf16 convert + exact fp32 row norms ----------------
// grid.y = 0 -> A, 1 -> B
__global__ __launch_bounds__(256) void prep_kernel(const float* __restrict__ A,
                                                   const float* __restrict__ B,
                                                   __hip_bfloat16* __restrict__ Abf,
                                                   __hip_bfloat16* __restrict__ Bbf,
                                                   float* __restrict__ na,
                                                   float* __restrict__ nb) {
    const float* x = blockIdx.y ? B : A;
    __hip_bfloat16* xb = blockIdx.y ? Bbf : Abf;
    float* norm = blockIdx.y ? nb : na;
    int lane = threadIdx.x & 63;
    int row  = blockIdx.x * 4 + (threadIdx.x >> 6);
    const float2 v = *(const float2*)(x + (size_t)row * DD + lane * 2);
    float s = v.x * v.x + v.y * v.y;
    __hip_bfloat162 h;
    h.x = __float2bfloat16(v.x);
    h.y = __float2bfloat16(v.y);
    *(__hip_bfloat162*)(xb + (size_t)row * DD + lane * 2) = h;
#pragma unroll
    for (int off = 32; off >= 1; off >>= 1) s += __shfl_xor(s, off, 64);
    if (lane == 0) norm[row] = s;
}

// ---------------- single fused MFMA distance pass ----------------
// Hinge algebra: max(0, 1 - pos + d) is NEVER clipped (d >= pos), so the loss
// reduces to: loss = 1 + T/(N*M) - (P_r + P_c)/16384 - 1/8192 with
// T = sum(d), P_r = sum(row mins), P_c = sum(col mins).
// One pass accumulates T (block atomicAdd) and row/col mins of d (u32 atomicMin).
// 128x128 tile per block, 4 waves (2x2), each wave 64x64 = 4x4 frags of 16x16x32.
// K staged in two 64-wide phases -> 32 KB LDS, conflict-free swizzled staging.
__global__ __launch_bounds__(256, 4) void dist_fused(
    const __hip_bfloat16* __restrict__ Ab, const __hip_bfloat16* __restrict__ Bb,
    const float* __restrict__ na, const float* __restrict__ nb,
    unsigned int* __restrict__ rowmin, unsigned int* __restrict__ colmin,
    float* __restrict__ partial) {
    __shared__ char lds[32768];
    char* ldsA = lds;
    char* ldsB = lds + 16384;
    const int tid = threadIdx.x;
    const int rowBase = blockIdx.y * 128;
    const int colBase = blockIdx.x * 128;

    const unsigned short* aG = (const unsigned short*)Ab + (size_t)rowBase * DD;
    const unsigned short* bG = (const unsigned short*)Bb + (size_t)colBase * DD;

    const int l = tid & 63, wid = tid >> 6;
    const int wr = wid >> 1, wc = wid & 1;   // wave 64x64 sub-tile
    const int g = l >> 4, c = l & 15;

    f32x4 acc[4][4];
#pragma unroll
    for (int mi = 0; mi < 4; ++mi)
#pragma unroll
        for (int ni = 0; ni < 4; ++ni) acc[mi][ni] = (f32x4)0.f;

#pragma unroll
    for (int p = 0; p < 2; ++p) {
        if (p) __syncthreads();   // previous compute done before overwrite
        // stage 128 rows x 64 bf16 (128 B/row) of A and B, XOR-swizzled
#pragma unroll
        for (int it = 0; it < 4; ++it) {
            int idx = tid + 256 * it;   // 0..1023
            int r = idx >> 3;           // row 0..127
            int c16 = idx & 7;          // 16B chunk in row
            int dst = r * 128 + ((c16 * 16) ^ ((r & 7) << 4));
            *(short8*)(ldsA + dst) = *(const short8*)(aG + r * DD + p * 64 + c16 * 8);
            *(short8*)(ldsB + dst) = *(const short8*)(bG + r * DD + p * 64 + c16 * 8);
        }
        __syncthreads();
#pragma unroll
        for (int kk = 0; kk < 2; ++kk) {
            short8 af[4], bf[4];
            const int kbyte = kk * 64 + g * 16;
#pragma unroll
            for (int mi = 0; mi < 4; ++mi) {
                int r = wr * 64 + mi * 16 + c;
                af[mi] = *(const short8*)(ldsA + r * 128 + (kbyte ^ ((r & 7) << 4)));
            }
#pragma unroll
            for (int ni = 0; ni < 4; ++ni) {
                int r2 = wc * 64 + ni * 16 + c;
                bf[ni] = *(const short8*)(ldsB + r2 * 128 + (kbyte ^ ((r2 & 7) << 4)));
            }
#pragma unroll
            for (int mi = 0; mi < 4; ++mi)
#pragma unroll
                for (int ni = 0; ni < 4; ++ni)
                    acc[mi][ni] = __builtin_amdgcn_mfma_f32_16x16x32_bf16(
                        af[mi], bf[ni], acc[mi][ni], 0, 0, 0);
        }
    }

    // out_row = row0 + mi*16 + g*4 + reg ; out_col = col0 + ni*16 + c
    const int row0 = rowBase + wr * 64;
    const int col0 = colBase + wc * 64;

    float nbc[4];
#pragma unroll
    for (int ni = 0; ni < 4; ++ni) nbc[ni] = nb[col0 + ni * 16 + c];

    float colm[4] = {BIGF, BIGF, BIGF, BIGF};
    float tot = 0.f;
#pragma unroll
    for (int mi = 0; mi < 4; ++mi) {
        const f32x4 na4 = *(const f32x4*)(na + row0 + mi * 16 + g * 4);
        float rowm[4] = {BIGF, BIGF, BIGF, BIGF};
#pragma unroll
        for (int ni = 0; ni < 4; ++ni) {
            f32x4 a = acc[mi][ni];
#pragma unroll
            for (int reg = 0; reg < 4; ++reg) {
                float d2 = fmaf(-2.0f, a[reg], na4[reg] + nbc[ni]);
                float d = __builtin_amdgcn_sqrtf(fmaxf(d2, 0.f));
                tot += d;
                rowm[reg] = fminf(rowm[reg], d);
                colm[ni] = fminf(colm[ni], d);
            }
        }
        // reduce row mins across the 16 c-lanes
#pragma unroll
        for (int reg = 0; reg < 4; ++reg) {
            float m = rowm[reg];
            m = fminf(m, __shfl_xor(m, 1, 64));
            m = fminf(m, __shfl_xor(m, 2, 64));
            m = fminf(m, __shfl_xor(m, 4, 64));
            m = fminf(m, __shfl_xor(m, 8, 64));
            rowm[reg] = m;
        }
        if (c == 0) {
#pragma unroll
            for (int reg = 0; reg < 4; ++reg)
                atomicMin(&rowmin[row0 + mi * 16 + g * 4 + reg],
                          __float_as_uint(rowm[reg]));
        }
    }
    // reduce col mins across the 4 g-groups
#pragma unroll
    for (int ni = 0; ni < 4; ++ni) {
        float m = colm[ni];
        m = fminf(m, __shfl_xor(m, 16, 64));
        m = fminf(m, __shfl_xor(m, 32, 64));
        if (g == 0) atomicMin(&colmin[col0 + ni * 16 + c], __float_as_uint(m));
    }
    // grand-total reduction: wave -> block -> global
#pragma unroll
    for (int off = 32; off >= 1; off >>= 1) tot += __shfl_xor(tot, off, 64);
    __syncthreads();   // all waves done reading LDS tiles
    float* red = (float*)lds;
    if (l == 0) red[wid] = tot;
    __syncthreads();
    if (tid == 0)
        atomicAdd(&partial[blockIdx.y], red[0] + red[1] + red[2] + red[3]);
}

// ---------------- finalize: combine mins + grand total into the scalar ----------------
__global__ __launch_bounds__(256) void finalize_kernel(const unsigned int* __restrict__ minbits,
                                                       const float* __restrict__ partial,
                                                       float* __restrict__ out) {
    const float* mins = (const float*)minbits;  // 16384 d-mins (rows then cols)
    float msum = 0.f;
    for (int i = threadIdx.x; i < 16384; i += 256) msum += mins[i];
    float cacc = msum * (-1.0f / 16384.0f);
    if (threadIdx.x < 64) cacc += partial[threadIdx.x] * (1.0f / 67108864.0f);
#pragma unroll
    for (int off = 32; off >= 1; off >>= 1) cacc += __shfl_xor(cacc, off, 64);
    __shared__ float red[4];
    int lane = threadIdx.x & 63, wave = threadIdx.x >> 6;
    if (lane == 0) red[wave] = cacc;
    __syncthreads();
    if (threadIdx.x == 0) {
        float t = red[0] + red[1] + red[2] + red[3];
        // loss = 1 - 1/8192 + T/(N*M) - (P_r+P_c)/16384
        out[0] = t + 1.0f - 1.0f / 8192.0f;
    }
}

extern "C" void kernel_launch(void* const* d_in, const int* in_sizes, int n_in,
                              void* d_out, int out_size, void* d_ws, size_t ws_size,
                              hipStream_t stream) {
    const float* A = (const float*)d_in[0];
    const float* B = (const float*)d_in[1];
    char* ws = (char*)d_ws;

    const size_t MB = 1024 * 1024;
    __hip_bfloat16* Abf = (__hip_bfloat16*)(ws);                 // 2 MB
    __hip_bfloat16* Bbf = (__hip_bfloat16*)(ws + 2 * MB);        // 2 MB
    float* na            = (float*)(ws + 4 * MB);                // 32 KB
    float* nb            = (float*)(ws + 4 * MB + 32768);        // 32 KB
    unsigned int* rowmin = (unsigned int*)(ws + 4 * MB + 65536); // 32 KB
    unsigned int* colmin = (unsigned int*)(ws + 4 * MB + 98304); // 32 KB (contig after rowmin)
    float* partial       = (float*)(ws + 4 * MB + 131072);       // 256 B

    hipMemsetAsync(rowmin, 0xFF, 65536, stream);   // rowmin+colmin -> u32 max
    hipMemsetAsync(partial, 0, 256, stream);

    dim3 pgrid(NN / 4, 2);
    prep_kernel<<<pgrid, 256, 0, stream>>>(A, B, Abf, Bbf, na, nb);

    dim3 grid(NN / 128, NN / 128);
    dist_fused<<<grid, 256, 0, stream>>>(Abf, Bbf, na, nb, rowmin, colmin, partial);

    finalize_kernel<<<1, 256, 0, stream>>>(rowmin, partial, (float*)d_out);
}